// Round 6
// baseline (288.701 us; speedup 1.0000x reference)
//
#include <hip/hip_runtime.h>
#include <hip/hip_bf16.h>
#include <math.h>

#define HIDDEN 1024
#define BATCH 32
#define SRC_LEN 2048
#define NROWS (BATCH * SRC_LEN)   // 65536
#define NEG_BIG -10000000000.0f

typedef __attribute__((ext_vector_type(8))) short bf16x8;
typedef __attribute__((ext_vector_type(4))) float f32x4;
typedef __attribute__((ext_vector_type(4))) unsigned uint32x4;

static __device__ __forceinline__ unsigned short f2bf(float f) {
  unsigned u = __float_as_uint(f);
  u = u + 0x7fffu + ((u >> 16) & 1u);
  return (unsigned short)(u >> 16);
}
static __device__ __forceinline__ unsigned pack2(float a, float b) {
  return (unsigned)f2bf(a) | ((unsigned)f2bf(b) << 16);
}

// ---------------------------------------------------------------------------
// Kernel 0: WT[n][h] = bf16(W_enc[h][n]) — one-time transpose+convert.
// ---------------------------------------------------------------------------
__global__ __launch_bounds__(256) void k_wt(
    const float* __restrict__ W, unsigned short* __restrict__ WT) {
  __shared__ float ts[64][65];
  const int hy = blockIdx.y * 64, nx = blockIdx.x * 64;
  const int tid = threadIdx.x;
#pragma unroll
  for (int i = 0; i < 16; ++i) {
    int idx = tid + i * 256, r = idx >> 6, c = idx & 63;
    ts[r][c] = W[(HIDDEN + hy + r) * HIDDEN + nx + c];
  }
  __syncthreads();
#pragma unroll
  for (int i = 0; i < 16; ++i) {
    int idx = tid + i * 256, rn = idx >> 6, ch = idx & 63;
    WT[(nx + rn) * HIDDEN + hy + ch] = f2bf(ts[ch][rn]);
  }
}

// ---------------------------------------------------------------------------
// Kernel 1a: dec partials. grid (16 ktiles, 16 hchunks), block 256.
// ---------------------------------------------------------------------------
__global__ __launch_bounds__(256) void k_dec_part(
    const float* __restrict__ dh, const float* __restrict__ W,
    float* __restrict__ decpart) {
  const int kl = threadIdx.x & 63;
  const int bq = threadIdx.x >> 6;
  const int k = blockIdx.x * 64 + kl;
  const int h0 = blockIdx.y * 64;
  __shared__ float dh_s[64][33];
#pragma unroll
  for (int i = 0; i < 8; ++i) {
    int idx = threadIdx.x + i * 256;
    int b = idx >> 6, hh = idx & 63;
    dh_s[hh][b] = dh[b * HIDDEN + h0 + hh];
  }
  __syncthreads();
  float acc[8] = {0.f, 0.f, 0.f, 0.f, 0.f, 0.f, 0.f, 0.f};
#pragma unroll
  for (int hh = 0; hh < 64; ++hh) {
    float w = W[(h0 + hh) * HIDDEN + k];
#pragma unroll
    for (int bb = 0; bb < 8; ++bb) acc[bb] += dh_s[hh][bq * 8 + bb] * w;
  }
#pragma unroll
  for (int bb = 0; bb < 8; ++bb)
    decpart[blockIdx.y * (BATCH * HIDDEN) + (bq * 8 + bb) * HIDDEN + k] = acc[bb];
}

__global__ __launch_bounds__(256) void k_dec_reduce(
    const float* __restrict__ decpart, const float* __restrict__ bias,
    float* __restrict__ out) {
  int e = blockIdx.x * 256 + threadIdx.x;
  float s = bias[e & (HIDDEN - 1)];
#pragma unroll
  for (int hc = 0; hc < 16; ++hc) s += decpart[hc * (BATCH * HIDDEN) + e];
  out[e] = s;
}

// ---------------------------------------------------------------------------
// Kernel 2 (dominant): pipelined MFMA bf16 GEMM fused with tanh + v_w dot.
// BM=128 x BN=256, BK=64, 8 waves. TRIPLE-buffered LDS, ONE raw s_barrier
// per K-step (lgkmcnt(0) only — vmcnt never drained: loads issued at t
// are consumed by ds_writes at t+1 => compiler emits counted vmcnt(8)).
// ---------------------------------------------------------------------------
#define BM 128
#define BN 256
#define BK 64
#define NT (HIDDEN / BK)   // 16

__global__ __launch_bounds__(512, 2) void k_energy_mfma(
    const float* __restrict__ enc, const unsigned short* __restrict__ WT,
    const float* __restrict__ dec_proj, const float* __restrict__ v_w,
    float* __restrict__ part) {
  __shared__ unsigned short As[3][BM * BK];  // 3 x 16 KB, swizzled 128B rows
  __shared__ unsigned short Bs[3][BN * BK];  // 3 x 32 KB
  __shared__ float red[4][BM];               // 2 KB  (total 146 KB)

  const int tid = threadIdx.x;
  const int lane = tid & 63;
  const int wid = tid >> 6;    // 0..7
  const int wm = wid >> 2;     // 0..1  (row half of 128)
  const int wn = wid & 3;      // 0..3  (col quarter of 256)
  const int l16 = lane & 15;
  const int kg = lane >> 4;    // 0..3

  // XCD-aware bijective swizzle: nwg=2048 (%8==0), 256 blocks per XCD chunk.
  const int bid = blockIdx.x;
  const int l = (bid & 7) * 256 + (bid >> 3);
  const int n0 = (l & 3) * BN;
  const int row0 = (l >> 2) * BM;
  const int b = row0 >> 11;

  f32x4 acc[4][4];
#pragma unroll
  for (int m = 0; m < 4; ++m)
#pragma unroll
    for (int n = 0; n < 4; ++n) acc[m][n] = (f32x4){0.f, 0.f, 0.f, 0.f};

  const float4* enc4 = (const float4*)enc;
  const uint32x4* WT4 = (const uint32x4*)WT;  // 16B = 8 bf16

  float4 pa0[4], pa1[4];
  uint32x4 pb0[4], pb1[4];

#define LOADAB(t, pa, pb)                                                 \
  do {                                                                    \
    int h0 = (t) * BK;                                                    \
    _Pragma("unroll") for (int i = 0; i < 4; ++i) {                       \
      int chunk = tid + i * 512;                                          \
      int r = chunk >> 4, c4 = chunk & 15;                                \
      pa[i] = enc4[(size_t)(row0 + r) * 256 + (h0 >> 2) + c4];            \
    }                                                                     \
    _Pragma("unroll") for (int i = 0; i < 4; ++i) {                       \
      int chunk = tid + i * 512;                                          \
      int nr = chunk >> 3, c16 = chunk & 7;                               \
      pb[i] = WT4[(size_t)(n0 + nr) * 128 + (h0 >> 3) + c16];             \
    }                                                                     \
  } while (0)

#define STOREAB(bufi, pa, pb)                                             \
  do {                                                                    \
    _Pragma("unroll") for (int i = 0; i < 4; ++i) {                       \
      int chunk = tid + i * 512;                                          \
      int r = chunk >> 4, c4 = chunk & 15;                                \
      unsigned off = r * 128 + ((c4 * 8) ^ ((r & 7) << 4));               \
      uint2 u;                                                            \
      u.x = pack2(pa[i].x, pa[i].y);                                      \
      u.y = pack2(pa[i].z, pa[i].w);                                      \
      *(uint2*)((char*)As[bufi] + off) = u;                               \
    }                                                                     \
    _Pragma("unroll") for (int i = 0; i < 4; ++i) {                       \
      int chunk = tid + i * 512;                                          \
      int nr = chunk >> 3, c16 = chunk & 7;                               \
      unsigned off = nr * 128 + ((c16 * 16) ^ ((nr & 7) << 4));           \
      *(uint32x4*)((char*)Bs[bufi] + off) = pb[i];                        \
    }                                                                     \
  } while (0)

#define MFMA_STEP(bufi)                                                   \
  do {                                                                    \
    __builtin_amdgcn_s_setprio(1);                                        \
    _Pragma("unroll") for (int ks = 0; ks < 2; ++ks) {                    \
      bf16x8 af[4], bv[4];                                                \
      _Pragma("unroll") for (int m = 0; m < 4; ++m) {                     \
        int r = wm * 64 + m * 16 + l16;                                   \
        unsigned off = r * 128 + ((ks * 64 + kg * 16) ^ ((r & 7) << 4));  \
        af[m] = *(const bf16x8*)((const char*)As[bufi] + off);            \
      }                                                                   \
      _Pragma("unroll") for (int n = 0; n < 4; ++n) {                     \
        int c = wn * 64 + n * 16 + l16;                                   \
        unsigned off = c * 128 + ((ks * 64 + kg * 16) ^ ((c & 7) << 4));  \
        bv[n] = *(const bf16x8*)((const char*)Bs[bufi] + off);            \
      }                                                                   \
      _Pragma("unroll") for (int m = 0; m < 4; ++m)                       \
          _Pragma("unroll") for (int n = 0; n < 4; ++n)                   \
              acc[m][n] = __builtin_amdgcn_mfma_f32_16x16x32_bf16(        \
                  af[m], bv[n], acc[m][n], 0, 0, 0);                      \
    }                                                                     \
    __builtin_amdgcn_s_setprio(0);                                        \
  } while (0)

#define SOFT_BARRIER()                                  \
  do {                                                  \
    asm volatile("s_waitcnt lgkmcnt(0)" ::: "memory");  \
    __builtin_amdgcn_s_barrier();                       \
  } while (0)

  // prologue: tiles 0,1 in flight; store 0; barrier (vmcnt NOT drained)
  LOADAB(0, pa0, pb0);
  LOADAB(1, pa1, pb1);
  STOREAB(0, pa0, pb0);
  SOFT_BARRIER();

  // main loop, unrolled x2 so register sets are statically named.
  // iter t:  LOAD(t+2)->set0, MFMA(buf q0), STORE set1(tile t+1)->buf q1
  // iter t+1: LOAD(t+3)->set1, MFMA(buf q1), STORE set0(tile t+2)->buf q2
  int q0 = 0;
  for (int t = 0; t < NT; t += 2) {
    int q1 = q0 + 1; if (q1 == 3) q1 = 0;
    int q2 = q1 + 1; if (q2 == 3) q2 = 0;

    if (t + 2 < NT) LOADAB(t + 2, pa0, pb0);
    MFMA_STEP(q0);
    if (t + 1 < NT) STOREAB(q1, pa1, pb1);
    SOFT_BARRIER();

    if (t + 3 < NT) LOADAB(t + 3, pa1, pb1);
    MFMA_STEP(q1);
    if (t + 2 < NT) STOREAB(q2, pa0, pb0);
    SOFT_BARRIER();

    q0 = q2;
  }

  // epilogue: tanh + v_w dot; C/D layout: col=l16, row=kg*4+reg
  float dv[4], vv[4];
#pragma unroll
  for (int n = 0; n < 4; ++n) {
    int kc = n0 + wn * 64 + n * 16 + l16;
    dv[n] = dec_proj[b * HIDDEN + kc];
    vv[n] = v_w[kc];
  }
#pragma unroll
  for (int m = 0; m < 4; ++m) {
#pragma unroll
    for (int r = 0; r < 4; ++r) {
      float p = 0.f;
#pragma unroll
      for (int n = 0; n < 4; ++n) {
        float x = dv[n] + acc[m][n][r];
        float t = 1.f - 2.f / (__expf(2.f * x) + 1.f);  // tanh, saturating
        p += t * vv[n];
      }
      p += __shfl_xor(p, 1);
      p += __shfl_xor(p, 2);
      p += __shfl_xor(p, 4);
      p += __shfl_xor(p, 8);
      if (l16 == 0) red[wn][wm * 64 + m * 16 + kg * 4 + r] = p;
    }
  }
  __syncthreads();
  if (tid < BM) {
    float s = red[0][tid] + red[1][tid] + red[2][tid] + red[3][tid];
    part[(size_t)(l & 3) * NROWS + row0 + tid] = s;
  }
#undef LOADAB
#undef STOREAB
#undef MFMA_STEP
#undef SOFT_BARRIER
}

// ---------------------------------------------------------------------------
// Kernel 3: sum 4 col-block partials + masked softmax. grid 32, block 256.
// ---------------------------------------------------------------------------
__global__ __launch_bounds__(256) void k_softmax(
    const float* __restrict__ part, const int* __restrict__ mask,
    float* __restrict__ out_w) {
  int b = blockIdx.x, tid = threadIdx.x;
  __shared__ float red[4], red2[4];
  float l[8];
  float m = -INFINITY;
#pragma unroll
  for (int j = 0; j < 8; ++j) {
    int s = tid + 256 * j;
    int row = b * SRC_LEN + s;
    float x = part[row] + part[NROWS + row] + part[2 * NROWS + row] +
              part[3 * NROWS + row];
    l[j] = (mask[row] == 0) ? NEG_BIG : x;
    m = fmaxf(m, l[j]);
  }
#pragma unroll
  for (int off = 32; off; off >>= 1) m = fmaxf(m, __shfl_xor(m, off));
  if ((tid & 63) == 0) red[tid >> 6] = m;
  __syncthreads();
  m = fmaxf(fmaxf(red[0], red[1]), fmaxf(red[2], red[3]));
  float sum = 0.f;
#pragma unroll
  for (int j = 0; j < 8; ++j) {
    l[j] = expf(l[j] - m);
    sum += l[j];
  }
#pragma unroll
  for (int off = 32; off; off >>= 1) sum += __shfl_xor(sum, off);
  if ((tid & 63) == 0) red2[tid >> 6] = sum;
  __syncthreads();
  sum = red2[0] + red2[1] + red2[2] + red2[3];
  float inv = 1.f / sum;
#pragma unroll
  for (int j = 0; j < 8; ++j) out_w[b * SRC_LEN + tid + 256 * j] = l[j] * inv;
}

// ---------------------------------------------------------------------------
// Kernel 4: context partials. grid (32,16), block 256.
// ---------------------------------------------------------------------------
__global__ __launch_bounds__(256) void k_ctx_partial(
    const float* __restrict__ w, const float* __restrict__ enc,
    float* __restrict__ part) {
  int b = blockIdx.x, sg = blockIdx.y, tid = threadIdx.x;
  const float4* enc4 = (const float4*)enc;
  float4 acc = {0.f, 0.f, 0.f, 0.f};
  int s0 = sg * 128;
#pragma unroll 4
  for (int s = 0; s < 128; ++s) {
    float ws = w[b * SRC_LEN + s0 + s];
    float4 e = enc4[(size_t)(b * SRC_LEN + s0 + s) * 256 + tid];
    acc.x += ws * e.x;
    acc.y += ws * e.y;
    acc.z += ws * e.z;
    acc.w += ws * e.w;
  }
  ((float4*)part)[(b * 16 + sg) * 256 + tid] = acc;
}

__global__ __launch_bounds__(256) void k_ctx_reduce(
    const float* __restrict__ part, float* __restrict__ ctx) {
  int b = blockIdx.x, tid = threadIdx.x;
  float4 acc = {0.f, 0.f, 0.f, 0.f};
#pragma unroll
  for (int sg = 0; sg < 16; ++sg) {
    float4 p = ((const float4*)part)[(b * 16 + sg) * 256 + tid];
    acc.x += p.x;
    acc.y += p.y;
    acc.z += p.z;
    acc.w += p.w;
  }
  ((float4*)ctx)[b * 256 + tid] = acc;
}

// ---------------------------------------------------------------------------
extern "C" void kernel_launch(void* const* d_in, const int* in_sizes, int n_in,
                              void* d_out, int out_size, void* d_ws, size_t ws_size,
                              hipStream_t stream) {
  const float* dh = (const float*)d_in[0];
  const float* enc = (const float*)d_in[1];
  const int* mask = (const int*)d_in[2];
  const float* attn_W = (const float*)d_in[3];
  const float* attn_b = (const float*)d_in[4];
  const float* v_w = (const float*)d_in[5];

  float* out_w = (float*)d_out;                   // [32][2048]
  float* out_ctx = (float*)d_out + NROWS;         // [32][1024]

  float* ws = (float*)d_ws;
  float* part = ws;                               // 4 * 65536
  float* dec_proj = ws + 4 * NROWS;               // 32768
  float* ctxpart = dec_proj + BATCH * HIDDEN;     // 524288
  float* decpart = ctxpart + BATCH * 16 * HIDDEN; // 524288
  unsigned short* WT = (unsigned short*)(decpart + 16 * BATCH * HIDDEN);

  k_wt<<<dim3(16, 16), 256, 0, stream>>>(attn_W, WT);
  k_dec_part<<<dim3(16, 16), 256, 0, stream>>>(dh, attn_W, decpart);
  k_dec_reduce<<<dim3(128), 256, 0, stream>>>(decpart, attn_b, dec_proj);
  k_energy_mfma<<<dim3(2048), 512, 0, stream>>>(enc, WT, dec_proj, v_w, part);
  k_softmax<<<dim3(BATCH), 256, 0, stream>>>(part, mask, out_w);
  k_ctx_partial<<<dim3(BATCH, 16), 256, 0, stream>>>(out_w, enc, ctxpart);
  k_ctx_reduce<<<dim3(BATCH), 256, 0, stream>>>(ctxpart, out_ctx);
}

// Round 7
// 228.794 us; speedup vs baseline: 1.2618x; 1.2618x over previous
//
#include <hip/hip_runtime.h>
#include <hip/hip_bf16.h>
#include <math.h>

#define HIDDEN 1024
#define BATCH 32
#define SRC_LEN 2048
#define NROWS (BATCH * SRC_LEN)   // 65536
#define NEG_BIG -10000000000.0f

typedef __attribute__((ext_vector_type(8))) short bf16x8;
typedef __attribute__((ext_vector_type(4))) float f32x4;
typedef __attribute__((ext_vector_type(4))) unsigned uint32x4;

static __device__ __forceinline__ unsigned short f2bf(float f) {
  unsigned u = __float_as_uint(f);
  u = u + 0x7fffu + ((u >> 16) & 1u);
  return (unsigned short)(u >> 16);
}

// single-instruction packed fp32->bf16 (RNE), gfx950
static __device__ __forceinline__ unsigned cvtpk(float lo, float hi) {
  unsigned r;
  asm("v_cvt_pk_bf16_f32 %0, %1, %2" : "=v"(r) : "v"(lo), "v"(hi));
  return r;
}

// async global->LDS, 16B per lane (CK-style address-space casts)
static __device__ __forceinline__ void gload16(const void* g, void* l) {
  __builtin_amdgcn_global_load_lds(
      reinterpret_cast<const __attribute__((address_space(1))) unsigned*>(
          reinterpret_cast<unsigned long long>(g)),
      reinterpret_cast<__attribute__((address_space(3))) unsigned*>(
          reinterpret_cast<unsigned long long>(l)),
      16, 0, 0);
}

// ---------------------------------------------------------------------------
// Kernel 0: WT[n][h] = bf16(W_enc[h][n]) — one-time transpose+convert.
// ---------------------------------------------------------------------------
__global__ __launch_bounds__(256) void k_wt(
    const float* __restrict__ W, unsigned short* __restrict__ WT) {
  __shared__ float ts[64][65];
  const int hy = blockIdx.y * 64, nx = blockIdx.x * 64;
  const int tid = threadIdx.x;
#pragma unroll
  for (int i = 0; i < 16; ++i) {
    int idx = tid + i * 256, r = idx >> 6, c = idx & 63;
    ts[r][c] = W[(HIDDEN + hy + r) * HIDDEN + nx + c];
  }
  __syncthreads();
#pragma unroll
  for (int i = 0; i < 16; ++i) {
    int idx = tid + i * 256, rn = idx >> 6, ch = idx & 63;
    WT[(nx + rn) * HIDDEN + hy + ch] = f2bf(ts[ch][rn]);
  }
}

// ---------------------------------------------------------------------------
// Kernel 1a/1b: dec_proj (parallel partials + reduce)
// ---------------------------------------------------------------------------
__global__ __launch_bounds__(256) void k_dec_part(
    const float* __restrict__ dh, const float* __restrict__ W,
    float* __restrict__ decpart) {
  const int kl = threadIdx.x & 63;
  const int bq = threadIdx.x >> 6;
  const int k = blockIdx.x * 64 + kl;
  const int h0 = blockIdx.y * 64;
  __shared__ float dh_s[64][33];
#pragma unroll
  for (int i = 0; i < 8; ++i) {
    int idx = threadIdx.x + i * 256;
    int b = idx >> 6, hh = idx & 63;
    dh_s[hh][b] = dh[b * HIDDEN + h0 + hh];
  }
  __syncthreads();
  float acc[8] = {0.f, 0.f, 0.f, 0.f, 0.f, 0.f, 0.f, 0.f};
#pragma unroll
  for (int hh = 0; hh < 64; ++hh) {
    float w = W[(h0 + hh) * HIDDEN + k];
#pragma unroll
    for (int bb = 0; bb < 8; ++bb) acc[bb] += dh_s[hh][bq * 8 + bb] * w;
  }
#pragma unroll
  for (int bb = 0; bb < 8; ++bb)
    decpart[blockIdx.y * (BATCH * HIDDEN) + (bq * 8 + bb) * HIDDEN + k] = acc[bb];
}

__global__ __launch_bounds__(256) void k_dec_reduce(
    const float* __restrict__ decpart, const float* __restrict__ bias,
    float* __restrict__ out) {
  int e = blockIdx.x * 256 + threadIdx.x;
  float s = bias[e & (HIDDEN - 1)];
#pragma unroll
  for (int hc = 0; hc < 16; ++hc) s += decpart[hc * (BATCH * HIDDEN) + e];
  out[e] = s;
}

// ---------------------------------------------------------------------------
// Kernel 2 (dominant): MFMA bf16 GEMM fused with tanh + v_w dot.
// 256x256 tile, BK=64, 8 waves (2m x 4n). Double-buffered LDS, one
// __syncthreads per K-step. B staged via global_load_lds (linear dest,
// inverse-swizzled source); A reg-staged with v_cvt_pk_bf16_f32.
// ---------------------------------------------------------------------------
#define BM 256
#define BN 256
#define BK 64
#define NT (HIDDEN / BK)   // 16

__global__ __launch_bounds__(512, 2) void k_energy_mfma(
    const float* __restrict__ enc, const unsigned short* __restrict__ WT,
    const float* __restrict__ dec_proj, const float* __restrict__ v_w,
    float* __restrict__ part) {
  __shared__ unsigned short As[2][BM * BK];  // 2 x 32 KB, 128B rows, swizzled
  __shared__ unsigned short Bs[2][BN * BK];  // 2 x 32 KB
  __shared__ float red[4][BM];               // 4 KB   (total 132 KB)

  const int tid = threadIdx.x;
  const int lane = tid & 63;
  const int wid = tid >> 6;    // 0..7
  const int wm = wid >> 2;     // 0..1  (row half of 256)
  const int wn = wid & 3;      // 0..3  (col quarter of 256)
  const int l16 = lane & 15;
  const int kg = lane >> 4;    // 0..3

  // XCD-aware bijective swizzle: nwg=1024 (%8==0), 128 per XCD chunk.
  const int bid = blockIdx.x;
  const int l = (bid & 7) * 128 + (bid >> 3);
  const int n0 = (l & 3) * BN;
  const int row0 = (l >> 2) * BM;
  const int b = row0 >> 11;

  f32x4 acc[8][4];
#pragma unroll
  for (int m = 0; m < 8; ++m)
#pragma unroll
    for (int n = 0; n < 4; ++n) acc[m][n] = (f32x4){0.f, 0.f, 0.f, 0.f};

  const float4* enc4 = (const float4*)enc;

  // A: thread covers rows rbase+64i (i=0..3), 32B-chunk c16=tid&7 of each row.
  const int rbase = tid >> 3;
  const int c16 = tid & 7;
  const float4* ea = enc4 + (size_t)(row0 + rbase) * 256 + c16 * 2;
  const unsigned aswz = ((unsigned)(rbase & 7)) << 4;
  const unsigned awoff = (unsigned)rbase * 128 + (((unsigned)c16 * 16) ^ aswz);

  // B: inverse-swizzled global source for linear global_load_lds dest.
  // lane covers LDS row c = i*64 + wid*8 + (lane>>3), 16B-chunk x = lane&7.
  const char* wb = (const char*)WT +
                   (size_t)(n0 + wid * 8 + (lane >> 3)) * 2048 +
                   ((((unsigned)(lane & 7)) * 16) ^ (((unsigned)(lane >> 3)) << 4));
  const unsigned bldsoff = (unsigned)wid * 1024;

  float4 pa[4][2];

#define STAGE_ISSUE(tile, pdst)                                            \
  do {                                                                     \
    _Pragma("unroll") for (int i = 0; i < 4; ++i)                          \
        gload16(wb + (size_t)i * 131072 + (size_t)(tile) * 128,            \
                (char*)Bs[pdst] + bldsoff + i * 8192);                     \
    _Pragma("unroll") for (int i = 0; i < 4; ++i) {                        \
      pa[i][0] = ea[(size_t)i * 16384 + (tile) * 16];                      \
      pa[i][1] = ea[(size_t)i * 16384 + (tile) * 16 + 1];                  \
    }                                                                      \
  } while (0)

#define STAGE_WRITE(pdst)                                                  \
  do {                                                                     \
    _Pragma("unroll") for (int i = 0; i < 4; ++i) {                        \
      uint32x4 q;                                                          \
      q.x = cvtpk(pa[i][0].x, pa[i][0].y);                                 \
      q.y = cvtpk(pa[i][0].z, pa[i][0].w);                                 \
      q.z = cvtpk(pa[i][1].x, pa[i][1].y);                                 \
      q.w = cvtpk(pa[i][1].z, pa[i][1].w);                                 \
      *(uint32x4*)((char*)As[pdst] + awoff + i * 8192) = q;                \
    }                                                                      \
  } while (0)

#define MFMA_STEP(p)                                                       \
  do {                                                                     \
    __builtin_amdgcn_s_setprio(1);                                         \
    _Pragma("unroll") for (int ks = 0; ks < 2; ++ks) {                     \
      bf16x8 af[8], bv[4];                                                 \
      _Pragma("unroll") for (int m = 0; m < 8; ++m) {                      \
        int r = wm * 128 + m * 16 + l16;                                   \
        unsigned off = (unsigned)r * 128 +                                 \
                       (((unsigned)(ks * 64 + kg * 16)) ^                  \
                        (((unsigned)(r & 7)) << 4));                       \
        af[m] = *(const bf16x8*)((const char*)As[p] + off);                \
      }                                                                    \
      _Pragma("unroll") for (int n = 0; n < 4; ++n) {                      \
        int c = wn * 64 + n * 16 + l16;                                    \
        unsigned off = (unsigned)c * 128 +                                 \
                       (((unsigned)(ks * 64 + kg * 16)) ^                  \
                        (((unsigned)(c & 7)) << 4));                       \
        bv[n] = *(const bf16x8*)((const char*)Bs[p] + off);                \
      }                                                                    \
      _Pragma("unroll") for (int m = 0; m < 8; ++m)                        \
          _Pragma("unroll") for (int n = 0; n < 4; ++n)                    \
              acc[m][n] = __builtin_amdgcn_mfma_f32_16x16x32_bf16(         \
                  af[m], bv[n], acc[m][n], 0, 0, 0);                       \
    }                                                                      \
    __builtin_amdgcn_s_setprio(0);                                         \
  } while (0)

#define STEP(tt, p)                                                        \
  do {                                                                     \
    if ((tt) + 1 < NT) STAGE_ISSUE((tt) + 1, (p) ^ 1);                     \
    MFMA_STEP(p);                                                          \
    if ((tt) + 1 < NT) STAGE_WRITE((p) ^ 1);                               \
    __syncthreads();                                                       \
  } while (0)

  // prologue: stage tile 0 into buffer 0
  STAGE_ISSUE(0, 0);
  STAGE_WRITE(0);
  __syncthreads();

  for (int t = 0; t < NT; t += 2) {
    STEP(t, 0);
    STEP(t + 1, 1);
  }

  // epilogue: tanh + v_w dot; C/D layout: col=l16, row=kg*4+reg
  float dv[4], vv[4];
#pragma unroll
  for (int n = 0; n < 4; ++n) {
    int kc = n0 + wn * 64 + n * 16 + l16;
    dv[n] = dec_proj[b * HIDDEN + kc];
    vv[n] = v_w[kc];
  }
#pragma unroll
  for (int m = 0; m < 8; ++m) {
#pragma unroll
    for (int r = 0; r < 4; ++r) {
      float p = 0.f;
#pragma unroll
      for (int n = 0; n < 4; ++n) {
        float x = dv[n] + acc[m][n][r];
        float t = 1.f - 2.f / (__expf(2.f * x) + 1.f);  // tanh, saturating
        p += t * vv[n];
      }
      p += __shfl_xor(p, 1);
      p += __shfl_xor(p, 2);
      p += __shfl_xor(p, 4);
      p += __shfl_xor(p, 8);
      if (l16 == 0) red[wn][wm * 128 + m * 16 + kg * 4 + r] = p;
    }
  }
  __syncthreads();
  if (tid < BM) {
    float s = red[0][tid] + red[1][tid] + red[2][tid] + red[3][tid];
    part[(size_t)(l & 3) * NROWS + row0 + tid] = s;
  }
#undef STAGE_ISSUE
#undef STAGE_WRITE
#undef MFMA_STEP
#undef STEP
}

// ---------------------------------------------------------------------------
// Kernel 3: sum 4 col-block partials + masked softmax. grid 32, block 256.
// ---------------------------------------------------------------------------
__global__ __launch_bounds__(256) void k_softmax(
    const float* __restrict__ part, const int* __restrict__ mask,
    float* __restrict__ out_w) {
  int b = blockIdx.x, tid = threadIdx.x;
  __shared__ float red[4], red2[4];
  float l[8];
  float m = -INFINITY;
#pragma unroll
  for (int j = 0; j < 8; ++j) {
    int s = tid + 256 * j;
    int row = b * SRC_LEN + s;
    float x = part[row] + part[NROWS + row] + part[2 * NROWS + row] +
              part[3 * NROWS + row];
    l[j] = (mask[row] == 0) ? NEG_BIG : x;
    m = fmaxf(m, l[j]);
  }
#pragma unroll
  for (int off = 32; off; off >>= 1) m = fmaxf(m, __shfl_xor(m, off));
  if ((tid & 63) == 0) red[tid >> 6] = m;
  __syncthreads();
  m = fmaxf(fmaxf(red[0], red[1]), fmaxf(red[2], red[3]));
  float sum = 0.f;
#pragma unroll
  for (int j = 0; j < 8; ++j) {
    l[j] = expf(l[j] - m);
    sum += l[j];
  }
#pragma unroll
  for (int off = 32; off; off >>= 1) sum += __shfl_xor(sum, off);
  if ((tid & 63) == 0) red2[tid >> 6] = sum;
  __syncthreads();
  sum = red2[0] + red2[1] + red2[2] + red2[3];
  float inv = 1.f / sum;
#pragma unroll
  for (int j = 0; j < 8; ++j) out_w[b * SRC_LEN + tid + 256 * j] = l[j] * inv;
}

// ---------------------------------------------------------------------------
// Kernel 4/5: context partials + reduce.
// ---------------------------------------------------------------------------
__global__ __launch_bounds__(256) void k_ctx_partial(
    const float* __restrict__ w, const float* __restrict__ enc,
    float* __restrict__ part) {
  int b = blockIdx.x, sg = blockIdx.y, tid = threadIdx.x;
  const float4* enc4 = (const float4*)enc;
  float4 acc = {0.f, 0.f, 0.f, 0.f};
  int s0 = sg * 128;
#pragma unroll 4
  for (int s = 0; s < 128; ++s) {
    float ws = w[b * SRC_LEN + s0 + s];
    float4 e = enc4[(size_t)(b * SRC_LEN + s0 + s) * 256 + tid];
    acc.x += ws * e.x;
    acc.y += ws * e.y;
    acc.z += ws * e.z;
    acc.w += ws * e.w;
  }
  ((float4*)part)[(b * 16 + sg) * 256 + tid] = acc;
}

__global__ __launch_bounds__(256) void k_ctx_reduce(
    const float* __restrict__ part, float* __restrict__ ctx) {
  int b = blockIdx.x, tid = threadIdx.x;
  float4 acc = {0.f, 0.f, 0.f, 0.f};
#pragma unroll
  for (int sg = 0; sg < 16; ++sg) {
    float4 p = ((const float4*)part)[(b * 16 + sg) * 256 + tid];
    acc.x += p.x;
    acc.y += p.y;
    acc.z += p.z;
    acc.w += p.w;
  }
  ((float4*)ctx)[b * 256 + tid] = acc;
}

// ---------------------------------------------------------------------------
extern "C" void kernel_launch(void* const* d_in, const int* in_sizes, int n_in,
                              void* d_out, int out_size, void* d_ws, size_t ws_size,
                              hipStream_t stream) {
  const float* dh = (const float*)d_in[0];
  const float* enc = (const float*)d_in[1];
  const int* mask = (const int*)d_in[2];
  const float* attn_W = (const float*)d_in[3];
  const float* attn_b = (const float*)d_in[4];
  const float* v_w = (const float*)d_in[5];

  float* out_w = (float*)d_out;                   // [32][2048]
  float* out_ctx = (float*)d_out + NROWS;         // [32][1024]

  float* ws = (float*)d_ws;
  float* part = ws;                               // 4 * 65536
  float* dec_proj = ws + 4 * NROWS;               // 32768
  float* ctxpart = dec_proj + BATCH * HIDDEN;     // 524288
  float* decpart = ctxpart + BATCH * 16 * HIDDEN; // 524288
  unsigned short* WT = (unsigned short*)(decpart + 16 * BATCH * HIDDEN);

  k_wt<<<dim3(16, 16), 256, 0, stream>>>(attn_W, WT);
  k_dec_part<<<dim3(16, 16), 256, 0, stream>>>(dh, attn_W, decpart);
  k_dec_reduce<<<dim3(128), 256, 0, stream>>>(decpart, attn_b, dec_proj);
  k_energy_mfma<<<dim3(1024), 512, 0, stream>>>(enc, WT, dec_proj, v_w, part);
  k_softmax<<<dim3(BATCH), 256, 0, stream>>>(part, mask, out_w);
  k_ctx_partial<<<dim3(BATCH, 16), 256, 0, stream>>>(out_w, enc, ctxpart);
  k_ctx_reduce<<<dim3(BATCH), 256, 0, stream>>>(ctxpart, out_ctx);
}